// Round 2
// 378.006 us; speedup vs baseline: 1.2389x; 1.2389x over previous
//
#include <hip/hip_runtime.h>
#include <hip/hip_bf16.h>

// PointNetConv on MI355X (gfx950) — round 9b (resubmit; r1 bench was an infra
// failure: "container failed twice", no profile). f32 inputs (measured r3-r7).
// Algebra: h1 = relu(A[row] - P[col]),  A = x@W1x + b1 + pos@W1p,  P = pos@W1p.
//
// r8 counters: pernode 237us, real SIMD busy ~10% (MfmaUtil/VALUBusy are per-CU
// normalized), FETCH 161MB consistent with per-XCD L2 misses on the A gather.
// => latency-bound: per-node serial chain (start/end -> srow -> A) restarted
// every ~2.2 chunks with only 3 waves/SIMD (VGPR=136).
//
// r9: pernode rewritten as a CONTINUOUS chunk stream across node boundaries:
//   level-2: srow in flight (2 chunks ahead), level-1: A-gather + next-node P
//   in flight (1 chunk ahead), level-0: compute. Node boundary = register
//   rotate + reduce/store, never a dependent reload chain.
// Register diet for 4 waves/SIMD (<=128 VGPR): P kept as bf16x8 (was f32[32]),
// ReLU computed in-place over xv (fA array eliminated).

typedef __bf16 bf16_t;
typedef __bf16 bf16x8 __attribute__((ext_vector_type(8)));
typedef float  f32x4  __attribute__((ext_vector_type(4)));

#define DPAD 16
#define CAP  128          // slots per node (Poisson(32) max deg ~70; guarded)

// ---------------- fallback scan chain (proven r7) ----------------
__global__ __launch_bounds__(256) void tilesum_kernel(const int* __restrict__ dpad,
                                                      int* __restrict__ tsum, int N) {
  __shared__ int ws[4];
  int tid = threadIdx.x;
  int i = blockIdx.x * 256 + tid;
  int v = (i < N) ? dpad[(long)i * DPAD] : 0;
#pragma unroll
  for (int off = 32; off > 0; off >>= 1) v += __shfl_down(v, off, 64);
  if ((tid & 63) == 0) ws[tid >> 6] = v;
  __syncthreads();
  if (tid == 0) tsum[blockIdx.x] = ws[0] + ws[1] + ws[2] + ws[3];
}

__global__ __launch_bounds__(256) void tscan_kernel(const int* __restrict__ tsum,
                                                    int* __restrict__ texcl,
                                                    int* __restrict__ startN, int nt_) {
  __shared__ int wsum[4];
  int tid = threadIdx.x, lane = tid & 63, w = tid >> 6;
  int v = (tid < nt_) ? tsum[tid] : 0;
  int s = v;
#pragma unroll
  for (int off = 1; off < 64; off <<= 1) {
    int t = __shfl_up(s, off, 64);
    if (lane >= off) s += t;
  }
  if (lane == 63) wsum[w] = s;
  __syncthreads();
  int add = 0;
  for (int j = 0; j < w; ++j) add += wsum[j];
  if (tid < nt_) texcl[tid] = add + s - v;
  if (tid == 0) *startN = wsum[0] + wsum[1] + wsum[2] + wsum[3];
}

__global__ __launch_bounds__(256) void scanout_kernel(int* __restrict__ dpad,
                                                      const int* __restrict__ texcl,
                                                      int* __restrict__ start, int N) {
  __shared__ int wsum[4];
  int tid = threadIdx.x, lane = tid & 63, w = tid >> 6;
  int i = blockIdx.x * 256 + tid;
  int v = (i < N) ? dpad[(long)i * DPAD] : 0;
  int s = v;
#pragma unroll
  for (int off = 1; off < 64; off <<= 1) {
    int t = __shfl_up(s, off, 64);
    if (lane >= off) s += t;
  }
  if (lane == 63) wsum[w] = s;
  __syncthreads();
  int add = texcl[blockIdx.x];
  for (int j = 0; j < w; ++j) add += wsum[j];
  int excl = add + s - v;
  if (i < N) { start[i] = excl; dpad[(long)i * DPAD + 8] = excl; }
}

__global__ __launch_bounds__(256) void scatter_kernel(const int* __restrict__ eidx,
                                                      int* __restrict__ dpad,
                                                      int* __restrict__ srow, int E) {
  int i = blockIdx.x * 256 + threadIdx.x;
  if (i < E) {
    int slot = atomicAdd(&dpad[(long)eidx[E + i] * DPAD + 8], 1);
    srow[slot] = eidx[i];
  }
}

__device__ __forceinline__ bf16x8 load_frag8f(const float* p) {
  float4 a = *(const float4*)p;
  float4 b = *(const float4*)(p + 4);
  bf16x8 r;
  r[0] = (bf16_t)a.x; r[1] = (bf16_t)a.y; r[2] = (bf16_t)a.z; r[3] = (bf16_t)a.w;
  r[4] = (bf16_t)b.x; r[5] = (bf16_t)b.y; r[6] = (bf16_t)b.z; r[7] = (bf16_t)b.w;
  return r;
}

// ---------------------------------------------------------------------------
// AP-GEMM body (shared by both fused kernels): A = x@W1x + b1 + pos@W1p,
// P = pos@W1p (both bf16, into d_out scratch). 64 nodes/block.
// ---------------------------------------------------------------------------
__device__ __forceinline__ void ap_gemm_body(
    const float* __restrict__ x, const float* __restrict__ pos,
    const float* __restrict__ W1, const float* __restrict__ b1,
    bf16_t* __restrict__ Abuf, bf16_t* __restrict__ Pbuf, int N, int blk)
{
  __shared__ bf16_t ws_[8][4][64][8];
  __shared__ float  w1ps[3][128];
  __shared__ float  bs_[128];
  __shared__ float  pos_s[64][3];

  const int tid = threadIdx.x;
  for (int it = tid; it < 8 * 4 * 64; it += 256) {
    int nt = it >> 8, kt = (it >> 6) & 3, l = it & 63;
    int n = nt * 16 + (l & 15), quad = l >> 4;
    bf16x8 v;
#pragma unroll
    for (int j = 0; j < 8; ++j) v[j] = (bf16_t)W1[(kt * 32 + quad * 8 + j) * 128 + n];
    *(bf16x8*)&ws_[nt][kt][l][0] = v;
  }
  for (int it = tid; it < 384; it += 256)
    w1ps[it >> 7][it & 127] = W1[(128 + (it >> 7)) * 128 + (it & 127)];
  if (tid < 128) bs_[tid] = b1[tid];
  {
    int g = blk * 192 + tid;
    if (tid < 192 && g < 3 * N) pos_s[tid / 3][tid % 3] = pos[g];
  }
  __syncthreads();

  const int w = tid >> 6, lane = tid & 63;
  const int m15 = lane & 15, quad = lane >> 4;

  int node_a = blk * 64 + w * 16 + m15;
  const float* xrow = x + (long)min(node_a, N - 1) * 128;
  bf16x8 a[4];
#pragma unroll
  for (int kt = 0; kt < 4; ++kt)
    a[kt] = load_frag8f(xrow + kt * 32 + quad * 8);

  f32x4 acc[8];
#pragma unroll
  for (int nt = 0; nt < 8; ++nt) acc[nt] = (f32x4){0.f, 0.f, 0.f, 0.f};
#pragma unroll
  for (int nt = 0; nt < 8; ++nt)
#pragma unroll
    for (int kt = 0; kt < 4; ++kt)
      acc[nt] = __builtin_amdgcn_mfma_f32_16x16x32_bf16(
          a[kt], *(const bf16x8*)&ws_[nt][kt][lane][0], acc[nt], 0, 0, 0);

#pragma unroll
  for (int r = 0; r < 4; ++r) {
    int nl = w * 16 + quad * 4 + r;
    int node = blk * 64 + nl;
    if (node < N) {
      float p0 = pos_s[nl][0], p1 = pos_s[nl][1], p2 = pos_s[nl][2];
#pragma unroll
      for (int nt = 0; nt < 8; ++nt) {
        int c = nt * 16 + m15;
        float pv = p0 * w1ps[0][c] + p1 * w1ps[1][c] + p2 * w1ps[2][c];
        long idx = (long)node * 128 + c;
        Abuf[idx] = (bf16_t)(acc[nt][r] + bs_[c] + pv);
        Pbuf[idx] = (bf16_t)pv;
      }
    }
  }
}

// Capacity path: scatter role + AP-GEMM role in one launch (overlap).
__global__ __launch_bounds__(256) void fused_cap_kernel(
    const float* __restrict__ x, const float* __restrict__ pos,
    const int* __restrict__ eidx, const float* __restrict__ W1,
    const float* __restrict__ b1, int* __restrict__ cursor,
    int* __restrict__ srowC, bf16_t* __restrict__ Abuf,
    bf16_t* __restrict__ Pbuf, int N, int E, int nodeBlocks)
{
  if ((int)blockIdx.x >= nodeBlocks) {      // ---- scatter role ----
    int i = ((int)blockIdx.x - nodeBlocks) * 256 + threadIdx.x;
    if (i < E) {
      int col = eidx[E + i];
      int slot = atomicAdd(&cursor[col], 1);
      if (slot < CAP) srowC[(long)col * CAP + slot] = eidx[i];
    }
    return;
  }
  ap_gemm_body(x, pos, W1, b1, Abuf, Pbuf, N, blockIdx.x);
}

// Fallback path: hist role + AP-GEMM role (r7-proven).
__global__ __launch_bounds__(256) void fused_hist_kernel(
    const float* __restrict__ x, const float* __restrict__ pos,
    const int* __restrict__ eidx, const float* __restrict__ W1,
    const float* __restrict__ b1, int* __restrict__ dpad,
    bf16_t* __restrict__ Abuf, bf16_t* __restrict__ Pbuf,
    int N, int E, int nodeBlocks)
{
  if ((int)blockIdx.x >= nodeBlocks) {
    int i = ((int)blockIdx.x - nodeBlocks) * 256 + threadIdx.x;
    if (i < E) atomicAdd(&dpad[(long)eidx[E + i] * DPAD], 1);
    return;
  }
  ap_gemm_body(x, pos, W1, b1, Abuf, Pbuf, N, blockIdx.x);
}

__global__ __launch_bounds__(256) void fillends_kernel(const int* __restrict__ cursor,
                                                       int* __restrict__ startC,
                                                       int* __restrict__ endC, int N) {
  int i = blockIdx.x * 256 + threadIdx.x;
  if (i < N) {
    int base = i * CAP;
    startC[i] = base;
    endC[i]   = base + min(cursor[i], CAP);
  }
}

// ---------------------------------------------------------------------------
// pernode r9: continuous (node,chunk) stream per wave over a contiguous node
// range. Three-level software pipeline crossing node boundaries:
//   level-2: srow for chunk t+2 in flight
//   level-1: A-row gather for chunk t+1 in flight; next node's P in flight
//   level-0: compute chunk t (relu in-place, 32 MFMA, running max)
// Node boundary: reduce+store, PnC <- PnN register rotate. Empty nodes are
// zero-stored inside the advance function (never on the hot path for this
// input: Poisson(32) degrees).
// ---------------------------------------------------------------------------
__global__ __launch_bounds__(256) void pernode_kernel(
    const bf16_t* __restrict__ Abuf, const bf16_t* __restrict__ Pbuf,
    const float* __restrict__ W2, const float* __restrict__ b2,
    const int* __restrict__ startp, const int* __restrict__ endp,
    const int* __restrict__ srow, bf16_t* __restrict__ maxbf, int N)
{
  __shared__ bf16_t w2s[8][4][64][8];   // 32 KB, B-fragment-major
  __shared__ float  b2s[128];

  const int tid = threadIdx.x;
  for (int it = tid; it < 8 * 4 * 64; it += 256) {
    int nt = it >> 8, kt = (it >> 6) & 3, l = it & 63;
    int ncol = nt * 16 + (l & 15), q = l >> 4;
    bf16x8 v;
#pragma unroll
    for (int j = 0; j < 8; ++j) v[j] = (bf16_t)W2[(kt * 32 + q * 8 + j) * 128 + ncol];
    *(bf16x8*)&w2s[nt][kt][l][0] = v;
  }
  if (tid < 128) b2s[tid] = b2[tid];
  __syncthreads();

  const int w = tid >> 6, lane = tid & 63;
  const int m15 = lane & 15, quad = lane >> 4;

  const int nslots = (int)gridDim.x * 4;
  const int slot   = (int)blockIdx.x * 4 + w;
  const int K      = (N + nslots - 1) / nslots;
  const int nBeg   = slot * K;
  const int nEnd   = min(N, nBeg + K);
  if (nBeg >= nEnd) return;

  // advance a (node, chunk) cursor; zero-stores empty nodes; freezes at nEnd
  auto adv = [&](int& n, int& c, int& e) {
    c += 16;
    if (c < e) return;
    for (;;) {
      if (++n >= nEnd) { n = nEnd; c -= 16; return; }   // frozen duplicate chunk
      int s_ = startp[n], e_ = endp[n];
      if (e_ > s_) { c = s_; e = e_; return; }
      if (quad == 0) {
#pragma unroll
        for (int nt = 0; nt < 8; ++nt)
          maxbf[(long)n * 128 + nt * 16 + m15] = (bf16_t)0.f;
      }
    }
  };

  // ---- prologue: fill the 3-level pipeline ----
  int n0 = nBeg - 1, c0 = -16, e0 = 0;
  adv(n0, c0, e0);                        // first non-empty node (or exhausted)
  if (n0 >= nEnd) return;

  bf16x8 PnC[4], PnN[4];
#pragma unroll
  for (int kt = 0; kt < 4; ++kt)
    PnC[kt] = *(const bf16x8*)(Pbuf + (long)n0 * 128 + kt * 32 + quad * 8);
  int r0 = srow[min(c0 + m15, e0 - 1)];

  int n1 = n0, c1 = c0, e1 = e0;
  adv(n1, c1, e1);

  bf16x8 xv[4];
#pragma unroll
  for (int kt = 0; kt < 4; ++kt)
    xv[kt] = *(const bf16x8*)(Abuf + (long)r0 * 128 + kt * 32 + quad * 8);

  int r1 = srow[min(c1 + m15, e1 - 1)];
#pragma unroll
  for (int kt = 0; kt < 4; ++kt) PnN[kt] = PnC[kt];     // safe default
  if (n1 != n0 && n1 < nEnd) {
#pragma unroll
    for (int kt = 0; kt < 4; ++kt)
      PnN[kt] = *(const bf16x8*)(Pbuf + (long)n1 * 128 + kt * 32 + quad * 8);
  }

  int n2 = n1, c2 = c1, e2 = e1;
  adv(n2, c2, e2);
  int r2 = srow[min(c2 + m15, e2 - 1)];

  float runmax[8];
#pragma unroll
  for (int nt = 0; nt < 8; ++nt) runmax[nt] = -3.4e38f;

  // ---- steady-state stream loop ----
  for (;;) {
    // issue A-gather for the level-1 chunk (r1 issued one iteration ago)
    bf16x8 xn[4];
#pragma unroll
    for (int kt = 0; kt < 4; ++kt)
      xn[kt] = *(const bf16x8*)(Abuf + (long)r1 * 128 + kt * 32 + quad * 8);

    // compute level-0 chunk: h1 = relu(A[row] - P[n0]) in place
#pragma unroll
    for (int kt = 0; kt < 4; ++kt) {
#pragma unroll
      for (int j = 0; j < 8; ++j)
        xv[kt][j] = (bf16_t)fmaxf((float)xv[kt][j] - (float)PnC[kt][j], 0.f);
    }

#pragma unroll
    for (int half = 0; half < 2; ++half) {
      f32x4 a0 = (f32x4){0.f, 0.f, 0.f, 0.f}, a1 = a0, a2 = a0, a3 = a0;
#pragma unroll
      for (int kt = 0; kt < 4; ++kt) {
        a0 = __builtin_amdgcn_mfma_f32_16x16x32_bf16(
            xv[kt], *(const bf16x8*)&w2s[half * 4 + 0][kt][lane][0], a0, 0, 0, 0);
        a1 = __builtin_amdgcn_mfma_f32_16x16x32_bf16(
            xv[kt], *(const bf16x8*)&w2s[half * 4 + 1][kt][lane][0], a1, 0, 0, 0);
        a2 = __builtin_amdgcn_mfma_f32_16x16x32_bf16(
            xv[kt], *(const bf16x8*)&w2s[half * 4 + 2][kt][lane][0], a2, 0, 0, 0);
        a3 = __builtin_amdgcn_mfma_f32_16x16x32_bf16(
            xv[kt], *(const bf16x8*)&w2s[half * 4 + 3][kt][lane][0], a3, 0, 0, 0);
      }
      runmax[half * 4 + 0] = fmaxf(runmax[half * 4 + 0],
          fmaxf(fmaxf(a0[0], a0[1]), fmaxf(a0[2], a0[3])));
      runmax[half * 4 + 1] = fmaxf(runmax[half * 4 + 1],
          fmaxf(fmaxf(a1[0], a1[1]), fmaxf(a1[2], a1[3])));
      runmax[half * 4 + 2] = fmaxf(runmax[half * 4 + 2],
          fmaxf(fmaxf(a2[0], a2[1]), fmaxf(a2[2], a2[3])));
      runmax[half * 4 + 3] = fmaxf(runmax[half * 4 + 3],
          fmaxf(fmaxf(a3[0], a3[1]), fmaxf(a3[2], a3[3])));
    }

    // node boundary: reduce + store + rotate P
    if (n1 != n0) {
#pragma unroll
      for (int nt = 0; nt < 8; ++nt) {
        float v = runmax[nt];
        v = fmaxf(v, __shfl_xor(v, 16, 64));
        v = fmaxf(v, __shfl_xor(v, 32, 64));
        v += b2s[nt * 16 + m15];
        if (quad == 0) maxbf[(long)n0 * 128 + nt * 16 + m15] = (bf16_t)v;
        runmax[nt] = -3.4e38f;
      }
#pragma unroll
      for (int kt = 0; kt < 4; ++kt) PnC[kt] = PnN[kt];
    }

    // rotate level-0 <- level-1
    n0 = n1; c0 = c1; e0 = e1;
    if (n0 >= nEnd) break;
#pragma unroll
    for (int kt = 0; kt < 4; ++kt) xv[kt] = xn[kt];

    // rotate level-1 <- level-2; issue next-node P if level-1 entered one
    n1 = n2; c1 = c2; e1 = e2; r1 = r2;
    if (n1 != n0 && n1 < nEnd) {
#pragma unroll
      for (int kt = 0; kt < 4; ++kt)
        PnN[kt] = *(const bf16x8*)(Pbuf + (long)n1 * 128 + kt * 32 + quad * 8);
    }

    // advance level-2; issue its srow
    adv(n2, c2, e2);
    r2 = srow[min(c2 + m15, e2 - 1)];
  }
}

// ---------------------------------------------------------------------------
// final: d_out = maxbf + x @ Wr + br   (f32 out)
// ---------------------------------------------------------------------------
__global__ __launch_bounds__(256) void final_gemm_kernel(
    const float* __restrict__ xin, const float* __restrict__ W,
    const float* __restrict__ bias, const bf16_t* __restrict__ maxv,
    float* __restrict__ dst, int N)
{
  __shared__ bf16_t ws_[8][4][64][8];
  __shared__ float  bs_[128];

  const int tid = threadIdx.x;
  for (int it = tid; it < 8 * 4 * 64; it += 256) {
    int nt = it >> 8, kt = (it >> 6) & 3, l = it & 63;
    int n = nt * 16 + (l & 15), quad = l >> 4;
    bf16x8 v;
#pragma unroll
    for (int j = 0; j < 8; ++j) v[j] = (bf16_t)W[(kt * 32 + quad * 8 + j) * 128 + n];
    *(bf16x8*)&ws_[nt][kt][l][0] = v;
  }
  if (tid < 128) bs_[tid] = bias[tid];
  __syncthreads();

  const int w = tid >> 6, lane = tid & 63;
  const int m15 = lane & 15, quad = lane >> 4;

  int node_a = blockIdx.x * 64 + w * 16 + m15;
  const float* xrow = xin + (long)min(node_a, N - 1) * 128;
  bf16x8 a[4];
#pragma unroll
  for (int kt = 0; kt < 4; ++kt)
    a[kt] = load_frag8f(xrow + kt * 32 + quad * 8);

  f32x4 acc[8];
#pragma unroll
  for (int nt = 0; nt < 8; ++nt) acc[nt] = (f32x4){0.f, 0.f, 0.f, 0.f};
#pragma unroll
  for (int nt = 0; nt < 8; ++nt)
#pragma unroll
    for (int kt = 0; kt < 4; ++kt)
      acc[nt] = __builtin_amdgcn_mfma_f32_16x16x32_bf16(
          a[kt], *(const bf16x8*)&ws_[nt][kt][lane][0], acc[nt], 0, 0, 0);

#pragma unroll
  for (int r = 0; r < 4; ++r) {
    int node = blockIdx.x * 64 + w * 16 + quad * 4 + r;
    if (node < N) {
#pragma unroll
      for (int nt = 0; nt < 8; ++nt) {
        int c = nt * 16 + m15;
        long idx = (long)node * 128 + c;
        dst[idx] = acc[nt][r] + bs_[c] + (float)maxv[idx];
      }
    }
  }
}

extern "C" void kernel_launch(void* const* d_in, const int* in_sizes, int n_in,
                              void* d_out, int out_size, void* d_ws, size_t ws_size,
                              hipStream_t stream) {
  (void)n_in; (void)out_size;
  const float* x   = (const float*)d_in[0];
  const float* pos = (const float*)d_in[1];
  const int*   eix = (const int*)d_in[2];
  const float* W1  = (const float*)d_in[3];
  const float* b1  = (const float*)d_in[4];
  const float* W2  = (const float*)d_in[5];
  const float* b2  = (const float*)d_in[6];
  const float* Wr  = (const float*)d_in[7];
  const float* br  = (const float*)d_in[8];

  const int N = in_sizes[0] / 128;
  const int E = in_sizes[2] / 2;

  bf16_t* Abuf = (bf16_t*)d_out;                      // [0, N*128) bf16
  bf16_t* Pbuf = (bf16_t*)d_out + (size_t)N * 128;    // [N*128, N*256) bf16

  const int nodeBlocks = (N + 63) / 64;
  const int edgeBlocks = (E + 255) / 256;
  const int nTiles     = (N + 255) / 256;

  // capacity-path ws need: maxbf N*256B + srowC N*CAP*4 + cursor/start/end 3*N*4
  const size_t needCap = (size_t)N * 256 + (size_t)N * CAP * 4 + (size_t)N * 12 + 1024;

  bf16_t* maxbf = (bf16_t*)d_ws;

  if (ws_size >= needCap) {
    // ---------------- capacity path ----------------
    int* srowC  = (int*)((char*)d_ws + (size_t)N * 256);
    int* cursor = srowC + (size_t)N * CAP;
    int* startC = cursor + N;
    int* endC   = startC + N;

    hipMemsetAsync(cursor, 0, (size_t)N * 4, stream);
    fused_cap_kernel<<<nodeBlocks + edgeBlocks, 256, 0, stream>>>(
        x, pos, eix, W1, b1, cursor, srowC, Abuf, Pbuf, N, E, nodeBlocks);
    fillends_kernel<<<nTiles, 256, 0, stream>>>(cursor, startC, endC, N);
    pernode_kernel<<<2048, 256, 0, stream>>>(Abuf, Pbuf, W2, b2, startC, endC,
                                             srowC, maxbf, N);
  } else {
    // ---------------- fallback: r7 hist+scan+scatter ----------------
    int* srow  = (int*)((char*)d_ws + (size_t)N * 256);
    int* dpad  = srow + E;
    int* start = dpad + (size_t)N * DPAD;
    int* tsum  = start + N + 1;
    int* texcl = tsum + 256;

    hipMemsetAsync(dpad, 0, (size_t)N * DPAD * 4, stream);
    fused_hist_kernel<<<nodeBlocks + edgeBlocks, 256, 0, stream>>>(
        x, pos, eix, W1, b1, dpad, Abuf, Pbuf, N, E, nodeBlocks);
    tilesum_kernel<<<nTiles, 256, 0, stream>>>(dpad, tsum, N);
    tscan_kernel<<<1, 256, 0, stream>>>(tsum, texcl, &start[N], nTiles);
    scanout_kernel<<<nTiles, 256, 0, stream>>>(dpad, texcl, start, N);
    scatter_kernel<<<edgeBlocks, 256, 0, stream>>>(eix, dpad, srow, E);
    pernode_kernel<<<2048, 256, 0, stream>>>(Abuf, Pbuf, W2, b2, start, start + 1,
                                             srow, maxbf, N);
  }

  final_gemm_kernel<<<nodeBlocks, 256, 0, stream>>>(x, Wr, br, maxbf,
                                                    (float*)d_out, N);
}

// Round 3
// 282.154 us; speedup vs baseline: 1.6598x; 1.3397x over previous
//
#include <hip/hip_runtime.h>
#include <hip/hip_bf16.h>

// PointNetConv on MI355X (gfx950) — round 10. f32 inputs.
// Algebra: h1 = relu(A[row] - P[col]),  A = x@W1x + b1 + pos@W1p,  P = pos@W1p.
//
// r9 result: 378us. pernode (continuous 3-level stream) dropped below 147us;
// fused_cap (scatter role) is now top at ~150us with MfmaUtil 0.4%, HBM 12%
// => random L2/MALL op-rate bound: 2 random ops/edge (atomic + scattered
// store) = 3.2M ops @ ~21G/s = 152us. Matches measurement.
//
// r10: eliminate per-edge random global ops entirely with LDS-staged
// two-pass bucketing:
//   passA (role in fusedA, overlapped with AP-GEMM): per 2048-edge tile,
//     LDS hist over 196 superbuckets (256 nodes each) -> LDS scan ->
//     LDS scatter -> ~196 aggregated global atomics (64B-padded counters)
//     -> coalesced segment writes to pairsBuf.
//   passB (1 block per superbucket): exact per-node CSR built in LDS
//     (hist 256 nodes, scan, LDS row scatter), coalesced srow/start/end out.
// pernode (r9, proven) and final_gemm unchanged.

typedef __bf16 bf16_t;
typedef __bf16 bf16x8 __attribute__((ext_vector_type(8)));
typedef float  f32x4  __attribute__((ext_vector_type(4)));

#define DPAD 16
#define NSB_SHIFT 8          // 256 nodes per superbucket
#define SBCAP 9216           // edges per superbucket cap (mean 8192, +11 sigma)
#define PA_TILE 2048         // edges per passA tile

// ---------------- fallback scan chain (proven r7) ----------------
__global__ __launch_bounds__(256) void tilesum_kernel(const int* __restrict__ dpad,
                                                      int* __restrict__ tsum, int N) {
  __shared__ int ws[4];
  int tid = threadIdx.x;
  int i = blockIdx.x * 256 + tid;
  int v = (i < N) ? dpad[(long)i * DPAD] : 0;
#pragma unroll
  for (int off = 32; off > 0; off >>= 1) v += __shfl_down(v, off, 64);
  if ((tid & 63) == 0) ws[tid >> 6] = v;
  __syncthreads();
  if (tid == 0) tsum[blockIdx.x] = ws[0] + ws[1] + ws[2] + ws[3];
}

__global__ __launch_bounds__(256) void tscan_kernel(const int* __restrict__ tsum,
                                                    int* __restrict__ texcl,
                                                    int* __restrict__ startN, int nt_) {
  __shared__ int wsum[4];
  int tid = threadIdx.x, lane = tid & 63, w = tid >> 6;
  int v = (tid < nt_) ? tsum[tid] : 0;
  int s = v;
#pragma unroll
  for (int off = 1; off < 64; off <<= 1) {
    int t = __shfl_up(s, off, 64);
    if (lane >= off) s += t;
  }
  if (lane == 63) wsum[w] = s;
  __syncthreads();
  int add = 0;
  for (int j = 0; j < w; ++j) add += wsum[j];
  if (tid < nt_) texcl[tid] = add + s - v;
  if (tid == 0) *startN = wsum[0] + wsum[1] + wsum[2] + wsum[3];
}

__global__ __launch_bounds__(256) void scanout_kernel(int* __restrict__ dpad,
                                                      const int* __restrict__ texcl,
                                                      int* __restrict__ start, int N) {
  __shared__ int wsum[4];
  int tid = threadIdx.x, lane = tid & 63, w = tid >> 6;
  int i = blockIdx.x * 256 + tid;
  int v = (i < N) ? dpad[(long)i * DPAD] : 0;
  int s = v;
#pragma unroll
  for (int off = 1; off < 64; off <<= 1) {
    int t = __shfl_up(s, off, 64);
    if (lane >= off) s += t;
  }
  if (lane == 63) wsum[w] = s;
  __syncthreads();
  int add = texcl[blockIdx.x];
  for (int j = 0; j < w; ++j) add += wsum[j];
  int excl = add + s - v;
  if (i < N) { start[i] = excl; dpad[(long)i * DPAD + 8] = excl; }
}

__global__ __launch_bounds__(256) void scatter_kernel(const int* __restrict__ eidx,
                                                      int* __restrict__ dpad,
                                                      int* __restrict__ srow, int E) {
  int i = blockIdx.x * 256 + threadIdx.x;
  if (i < E) {
    int slot = atomicAdd(&dpad[(long)eidx[E + i] * DPAD + 8], 1);
    srow[slot] = eidx[i];
  }
}

__device__ __forceinline__ bf16x8 load_frag8f(const float* p) {
  float4 a = *(const float4*)p;
  float4 b = *(const float4*)(p + 4);
  bf16x8 r;
  r[0] = (bf16_t)a.x; r[1] = (bf16_t)a.y; r[2] = (bf16_t)a.z; r[3] = (bf16_t)a.w;
  r[4] = (bf16_t)b.x; r[5] = (bf16_t)b.y; r[6] = (bf16_t)b.z; r[7] = (bf16_t)b.w;
  return r;
}

// ---------------------------------------------------------------------------
// Shared-memory structs for the role-split kernels (union via char buffer).
// ---------------------------------------------------------------------------
struct GemmSmem {
  bf16_t ws_[8][4][64][8];   // 32768 B
  float  w1ps[3][128];       //  1536 B
  float  bs_[128];           //   512 B
  float  pos_s[64][3];       //   768 B
};                           // 35584 B

struct PassASmem {
  long long sorted[PA_TILE]; // 16384 B
  int hist[256];
  int off_[256];
  int cur[256];
  int gbase[256];
  int scanb[256];
};                           // 21504 B

#define SMEM_BYTES 35840

// ---------------------------------------------------------------------------
// AP-GEMM body: A = x@W1x + b1 + pos@W1p, P = pos@W1p (bf16 into d_out).
// 64 nodes/block, 256 threads.
// ---------------------------------------------------------------------------
__device__ __forceinline__ void ap_gemm_body(
    const float* __restrict__ x, const float* __restrict__ pos,
    const float* __restrict__ W1, const float* __restrict__ b1,
    bf16_t* __restrict__ Abuf, bf16_t* __restrict__ Pbuf, int N, int blk,
    char* smem)
{
  GemmSmem* G = (GemmSmem*)smem;
  const int tid = threadIdx.x;
  for (int it = tid; it < 8 * 4 * 64; it += 256) {
    int nt = it >> 8, kt = (it >> 6) & 3, l = it & 63;
    int n = nt * 16 + (l & 15), quad = l >> 4;
    bf16x8 v;
#pragma unroll
    for (int j = 0; j < 8; ++j) v[j] = (bf16_t)W1[(kt * 32 + quad * 8 + j) * 128 + n];
    *(bf16x8*)&G->ws_[nt][kt][l][0] = v;
  }
  for (int it = tid; it < 384; it += 256)
    G->w1ps[it >> 7][it & 127] = W1[(128 + (it >> 7)) * 128 + (it & 127)];
  if (tid < 128) G->bs_[tid] = b1[tid];
  {
    int g = blk * 192 + tid;
    if (tid < 192 && g < 3 * N) G->pos_s[tid / 3][tid % 3] = pos[g];
  }
  __syncthreads();

  const int w = tid >> 6, lane = tid & 63;
  const int m15 = lane & 15, quad = lane >> 4;

  int node_a = blk * 64 + w * 16 + m15;
  const float* xrow = x + (long)min(node_a, N - 1) * 128;
  bf16x8 a[4];
#pragma unroll
  for (int kt = 0; kt < 4; ++kt)
    a[kt] = load_frag8f(xrow + kt * 32 + quad * 8);

  f32x4 acc[8];
#pragma unroll
  for (int nt = 0; nt < 8; ++nt) acc[nt] = (f32x4){0.f, 0.f, 0.f, 0.f};
#pragma unroll
  for (int nt = 0; nt < 8; ++nt)
#pragma unroll
    for (int kt = 0; kt < 4; ++kt)
      acc[nt] = __builtin_amdgcn_mfma_f32_16x16x32_bf16(
          a[kt], *(const bf16x8*)&G->ws_[nt][kt][lane][0], acc[nt], 0, 0, 0);

#pragma unroll
  for (int r = 0; r < 4; ++r) {
    int nl = w * 16 + quad * 4 + r;
    int node = blk * 64 + nl;
    if (node < N) {
      float p0 = G->pos_s[nl][0], p1 = G->pos_s[nl][1], p2 = G->pos_s[nl][2];
#pragma unroll
      for (int nt = 0; nt < 8; ++nt) {
        int c = nt * 16 + m15;
        float pv = p0 * G->w1ps[0][c] + p1 * G->w1ps[1][c] + p2 * G->w1ps[2][c];
        long idx = (long)node * 128 + c;
        Abuf[idx] = (bf16_t)(acc[nt][r] + G->bs_[c] + pv);
        Pbuf[idx] = (bf16_t)pv;
      }
    }
  }
}

// ---------------------------------------------------------------------------
// passA body: tile-sort PA_TILE edges into NSB superbuckets, all random ops
// in LDS; ~NSB aggregated global atomics per tile; coalesced segment writes.
// ---------------------------------------------------------------------------
__device__ __forceinline__ void passa_body(
    const int* __restrict__ eidx, long long* __restrict__ pairsBuf,
    int* __restrict__ superCursor, int E, int tile, char* smem)
{
  PassASmem* S = (PassASmem*)smem;
  const int tid = threadIdx.x;
  const int base = tile * PA_TILE;
  const int cnt_t = min(PA_TILE, E - base);

  for (int j = tid; j < 256; j += 256) S->hist[j] = 0;
  __syncthreads();

  int myrow[8], mycol[8];
#pragma unroll
  for (int k = 0; k < 8; ++k) {
    int idx = k * 256 + tid;
    int i = base + idx;
    if (idx < cnt_t) {
      myrow[k] = eidx[i];
      mycol[k] = eidx[E + i];
      atomicAdd(&S->hist[mycol[k] >> NSB_SHIFT], 1);
    } else mycol[k] = -1;
  }
  __syncthreads();

  // exclusive scan of hist[0..255] (Hillis-Steele)
  int v = S->hist[tid];
  S->scanb[tid] = v;
  __syncthreads();
  for (int d = 1; d < 256; d <<= 1) {
    int t = (tid >= d) ? S->scanb[tid - d] : 0;
    __syncthreads();
    S->scanb[tid] += t;
    __syncthreads();
  }
  int excl = S->scanb[tid] - v;
  S->off_[tid] = excl;
  S->cur[tid]  = excl;
  // claim global segment space (64B-padded counters; rare & aggregated)
  S->gbase[tid] = (v > 0) ? atomicAdd(&superCursor[tid * 16], v) : 0;
  __syncthreads();

  // scatter into LDS sorted order
#pragma unroll
  for (int k = 0; k < 8; ++k) {
    if (mycol[k] >= 0) {
      int sb = mycol[k] >> NSB_SHIFT;
      int pos = atomicAdd(&S->cur[sb], 1);
      S->sorted[pos] = ((long long)(unsigned)mycol[k] << 32) |
                       (unsigned long long)(unsigned)myrow[k];
    }
  }
  __syncthreads();

  // write out: consecutive idx of same sb -> consecutive global addresses
#pragma unroll
  for (int k = 0; k < 8; ++k) {
    int idx = k * 256 + tid;
    if (idx < cnt_t) {
      long long p = S->sorted[idx];
      int sb = (int)(p >> 32) >> NSB_SHIFT;
      int local = idx - S->off_[sb];
      long g = (long)S->gbase[sb] + local;
      if (g < SBCAP) pairsBuf[(long)sb * SBCAP + g] = p;
    }
  }
}

// fusedA: AP-GEMM role + passA role in one launch (overlap).
__global__ __launch_bounds__(256) void fusedA_kernel(
    const float* __restrict__ x, const float* __restrict__ pos,
    const int* __restrict__ eidx, const float* __restrict__ W1,
    const float* __restrict__ b1, long long* __restrict__ pairsBuf,
    int* __restrict__ superCursor, bf16_t* __restrict__ Abuf,
    bf16_t* __restrict__ Pbuf, int N, int E, int nodeBlocks)
{
  __shared__ __align__(16) char smem[SMEM_BYTES];
  if ((int)blockIdx.x >= nodeBlocks) {
    passa_body(eidx, pairsBuf, superCursor, E, (int)blockIdx.x - nodeBlocks, smem);
    return;
  }
  ap_gemm_body(x, pos, W1, b1, Abuf, Pbuf, N, blockIdx.x, smem);
}

// Fallback path: hist role + AP-GEMM role (r7-proven).
__global__ __launch_bounds__(256) void fused_hist_kernel(
    const float* __restrict__ x, const float* __restrict__ pos,
    const int* __restrict__ eidx, const float* __restrict__ W1,
    const float* __restrict__ b1, int* __restrict__ dpad,
    bf16_t* __restrict__ Abuf, bf16_t* __restrict__ Pbuf,
    int N, int E, int nodeBlocks)
{
  __shared__ __align__(16) char smem[SMEM_BYTES];
  if ((int)blockIdx.x >= nodeBlocks) {
    int i = ((int)blockIdx.x - nodeBlocks) * 256 + threadIdx.x;
    if (i < E) atomicAdd(&dpad[(long)eidx[E + i] * DPAD], 1);
    return;
  }
  ap_gemm_body(x, pos, W1, b1, Abuf, Pbuf, N, blockIdx.x, smem);
}

// ---------------------------------------------------------------------------
// passB: one block per superbucket; exact per-node CSR built in LDS.
// ---------------------------------------------------------------------------
__global__ __launch_bounds__(256) void passb_kernel(
    const long long* __restrict__ pairsBuf, const int* __restrict__ superCursor,
    int* __restrict__ srow, int* __restrict__ startB, int* __restrict__ endB,
    int N)
{
  __shared__ int rows[SBCAP];
  __shared__ int deg[256], off_[256], scanb[256];
  const int sb = blockIdx.x;
  const int tid = threadIdx.x;
  const int nbase = sb << NSB_SHIFT;
  const int count = min(superCursor[sb * 16], SBCAP);
  const long long* P = pairsBuf + (long)sb * SBCAP;

  deg[tid] = 0;
  __syncthreads();
  for (int i = tid; i < count; i += 256)
    atomicAdd(&deg[(int)(P[i] >> 32) - nbase], 1);
  __syncthreads();

  int v = deg[tid];
  scanb[tid] = v;
  __syncthreads();
  for (int d = 1; d < 256; d <<= 1) {
    int t = (tid >= d) ? scanb[tid - d] : 0;
    __syncthreads();
    scanb[tid] += t;
    __syncthreads();
  }
  int excl = scanb[tid] - v;
  off_[tid] = excl;
  deg[tid]  = excl;          // reuse as running cursor
  int n = nbase + tid;
  if (n < N) {
    int st = sb * SBCAP + excl;
    startB[n] = st;
    endB[n]   = st + v;
  }
  __syncthreads();

  for (int i = tid; i < count; i += 256) {
    long long p = P[i];
    int slot = atomicAdd(&deg[(int)(p >> 32) - nbase], 1);
    rows[slot] = (int)(p & 0xffffffffll);
  }
  __syncthreads();

  const int gb = sb * SBCAP;
  for (int i = tid; i < count; i += 256) srow[gb + i] = rows[i];
}

// ---------------------------------------------------------------------------
// pernode r9 (unchanged, proven): continuous (node,chunk) stream per wave.
// ---------------------------------------------------------------------------
__global__ __launch_bounds__(256) void pernode_kernel(
    const bf16_t* __restrict__ Abuf, const bf16_t* __restrict__ Pbuf,
    const float* __restrict__ W2, const float* __restrict__ b2,
    const int* __restrict__ startp, const int* __restrict__ endp,
    const int* __restrict__ srow, bf16_t* __restrict__ maxbf, int N)
{
  __shared__ bf16_t w2s[8][4][64][8];   // 32 KB, B-fragment-major
  __shared__ float  b2s[128];

  const int tid = threadIdx.x;
  for (int it = tid; it < 8 * 4 * 64; it += 256) {
    int nt = it >> 8, kt = (it >> 6) & 3, l = it & 63;
    int ncol = nt * 16 + (l & 15), q = l >> 4;
    bf16x8 v;
#pragma unroll
    for (int j = 0; j < 8; ++j) v[j] = (bf16_t)W2[(kt * 32 + q * 8 + j) * 128 + ncol];
    *(bf16x8*)&w2s[nt][kt][l][0] = v;
  }
  if (tid < 128) b2s[tid] = b2[tid];
  __syncthreads();

  const int w = tid >> 6, lane = tid & 63;
  const int m15 = lane & 15, quad = lane >> 4;

  const int nslots = (int)gridDim.x * 4;
  const int slot   = (int)blockIdx.x * 4 + w;
  const int K      = (N + nslots - 1) / nslots;
  const int nBeg   = slot * K;
  const int nEnd   = min(N, nBeg + K);
  if (nBeg >= nEnd) return;

  auto adv = [&](int& n, int& c, int& e) {
    c += 16;
    if (c < e) return;
    for (;;) {
      if (++n >= nEnd) { n = nEnd; c -= 16; return; }
      int s_ = startp[n], e_ = endp[n];
      if (e_ > s_) { c = s_; e = e_; return; }
      if (quad == 0) {
#pragma unroll
        for (int nt = 0; nt < 8; ++nt)
          maxbf[(long)n * 128 + nt * 16 + m15] = (bf16_t)0.f;
      }
    }
  };

  int n0 = nBeg - 1, c0 = -16, e0 = 0;
  adv(n0, c0, e0);
  if (n0 >= nEnd) return;

  bf16x8 PnC[4], PnN[4];
#pragma unroll
  for (int kt = 0; kt < 4; ++kt)
    PnC[kt] = *(const bf16x8*)(Pbuf + (long)n0 * 128 + kt * 32 + quad * 8);
  int r0 = srow[min(c0 + m15, e0 - 1)];

  int n1 = n0, c1 = c0, e1 = e0;
  adv(n1, c1, e1);

  bf16x8 xv[4];
#pragma unroll
  for (int kt = 0; kt < 4; ++kt)
    xv[kt] = *(const bf16x8*)(Abuf + (long)r0 * 128 + kt * 32 + quad * 8);

  int r1 = srow[min(c1 + m15, e1 - 1)];
#pragma unroll
  for (int kt = 0; kt < 4; ++kt) PnN[kt] = PnC[kt];
  if (n1 != n0 && n1 < nEnd) {
#pragma unroll
    for (int kt = 0; kt < 4; ++kt)
      PnN[kt] = *(const bf16x8*)(Pbuf + (long)n1 * 128 + kt * 32 + quad * 8);
  }

  int n2 = n1, c2 = c1, e2 = e1;
  adv(n2, c2, e2);
  int r2 = srow[min(c2 + m15, e2 - 1)];

  float runmax[8];
#pragma unroll
  for (int nt = 0; nt < 8; ++nt) runmax[nt] = -3.4e38f;

  for (;;) {
    bf16x8 xn[4];
#pragma unroll
    for (int kt = 0; kt < 4; ++kt)
      xn[kt] = *(const bf16x8*)(Abuf + (long)r1 * 128 + kt * 32 + quad * 8);

#pragma unroll
    for (int kt = 0; kt < 4; ++kt) {
#pragma unroll
      for (int j = 0; j < 8; ++j)
        xv[kt][j] = (bf16_t)fmaxf((float)xv[kt][j] - (float)PnC[kt][j], 0.f);
    }

#pragma unroll
    for (int half = 0; half < 2; ++half) {
      f32x4 a0 = (f32x4){0.f, 0.f, 0.f, 0.f}, a1 = a0, a2 = a0, a3 = a0;
#pragma unroll
      for (int kt = 0; kt < 4; ++kt) {
        a0 = __builtin_amdgcn_mfma_f32_16x16x32_bf16(
            xv[kt], *(const bf16x8*)&w2s[half * 4 + 0][kt][lane][0], a0, 0, 0, 0);
        a1 = __builtin_amdgcn_mfma_f32_16x16x32_bf16(
            xv[kt], *(const bf16x8*)&w2s[half * 4 + 1][kt][lane][0], a1, 0, 0, 0);
        a2 = __builtin_amdgcn_mfma_f32_16x16x32_bf16(
            xv[kt], *(const bf16x8*)&w2s[half * 4 + 2][kt][lane][0], a2, 0, 0, 0);
        a3 = __builtin_amdgcn_mfma_f32_16x16x32_bf16(
            xv[kt], *(const bf16x8*)&w2s[half * 4 + 3][kt][lane][0], a3, 0, 0, 0);
      }
      runmax[half * 4 + 0] = fmaxf(runmax[half * 4 + 0],
          fmaxf(fmaxf(a0[0], a0[1]), fmaxf(a0[2], a0[3])));
      runmax[half * 4 + 1] = fmaxf(runmax[half * 4 + 1],
          fmaxf(fmaxf(a1[0], a1[1]), fmaxf(a1[2], a1[3])));
      runmax[half * 4 + 2] = fmaxf(runmax[half * 4 + 2],
          fmaxf(fmaxf(a2[0], a2[1]), fmaxf(a2[2], a2[3])));
      runmax[half * 4 + 3] = fmaxf(runmax[half * 4 + 3],
          fmaxf(fmaxf(a3[0], a3[1]), fmaxf(a3[2], a3[3])));
    }

    if (n1 != n0) {
#pragma unroll
      for (int nt = 0; nt < 8; ++nt) {
        float v = runmax[nt];
        v = fmaxf(v, __shfl_xor(v, 16, 64));
        v = fmaxf(v, __shfl_xor(v, 32, 64));
        v += b2s[nt * 16 + m15];
        if (quad == 0) maxbf[(long)n0 * 128 + nt * 16 + m15] = (bf16_t)v;
        runmax[nt] = -3.4e38f;
      }
#pragma unroll
      for (int kt = 0; kt < 4; ++kt) PnC[kt] = PnN[kt];
    }

    n0 = n1; c0 = c1; e0 = e1;
    if (n0 >= nEnd) break;
#pragma unroll
    for (int kt = 0; kt < 4; ++kt) xv[kt] = xn[kt];

    n1 = n2; c1 = c2; e1 = e2; r1 = r2;
    if (n1 != n0 && n1 < nEnd) {
#pragma unroll
      for (int kt = 0; kt < 4; ++kt)
        PnN[kt] = *(const bf16x8*)(Pbuf + (long)n1 * 128 + kt * 32 + quad * 8);
    }

    adv(n2, c2, e2);
    r2 = srow[min(c2 + m15, e2 - 1)];
  }
}

// ---------------------------------------------------------------------------
// final: d_out = maxbf + x @ Wr + br   (f32 out)
// ---------------------------------------------------------------------------
__global__ __launch_bounds__(256) void final_gemm_kernel(
    const float* __restrict__ xin, const float* __restrict__ W,
    const float* __restrict__ bias, const bf16_t* __restrict__ maxv,
    float* __restrict__ dst, int N)
{
  __shared__ bf16_t ws_[8][4][64][8];
  __shared__ float  bs_[128];

  const int tid = threadIdx.x;
  for (int it = tid; it < 8 * 4 * 64; it += 256) {
    int nt = it >> 8, kt = (it >> 6) & 3, l = it & 63;
    int n = nt * 16 + (l & 15), quad = l >> 4;
    bf16x8 v;
#pragma unroll
    for (int j = 0; j < 8; ++j) v[j] = (bf16_t)W[(kt * 32 + quad * 8 + j) * 128 + n];
    *(bf16x8*)&ws_[nt][kt][l][0] = v;
  }
  if (tid < 128) bs_[tid] = bias[tid];
  __syncthreads();

  const int w = tid >> 6, lane = tid & 63;
  const int m15 = lane & 15, quad = lane >> 4;

  int node_a = blockIdx.x * 64 + w * 16 + m15;
  const float* xrow = xin + (long)min(node_a, N - 1) * 128;
  bf16x8 a[4];
#pragma unroll
  for (int kt = 0; kt < 4; ++kt)
    a[kt] = load_frag8f(xrow + kt * 32 + quad * 8);

  f32x4 acc[8];
#pragma unroll
  for (int nt = 0; nt < 8; ++nt) acc[nt] = (f32x4){0.f, 0.f, 0.f, 0.f};
#pragma unroll
  for (int nt = 0; nt < 8; ++nt)
#pragma unroll
    for (int kt = 0; kt < 4; ++kt)
      acc[nt] = __builtin_amdgcn_mfma_f32_16x16x32_bf16(
          a[kt], *(const bf16x8*)&ws_[nt][kt][lane][0], acc[nt], 0, 0, 0);

#pragma unroll
  for (int r = 0; r < 4; ++r) {
    int node = blockIdx.x * 64 + w * 16 + quad * 4 + r;
    if (node < N) {
#pragma unroll
      for (int nt = 0; nt < 8; ++nt) {
        int c = nt * 16 + m15;
        long idx = (long)node * 128 + c;
        dst[idx] = acc[nt][r] + bs_[c] + (float)maxv[idx];
      }
    }
  }
}

extern "C" void kernel_launch(void* const* d_in, const int* in_sizes, int n_in,
                              void* d_out, int out_size, void* d_ws, size_t ws_size,
                              hipStream_t stream) {
  (void)n_in; (void)out_size;
  const float* x   = (const float*)d_in[0];
  const float* pos = (const float*)d_in[1];
  const int*   eix = (const int*)d_in[2];
  const float* W1  = (const float*)d_in[3];
  const float* b1  = (const float*)d_in[4];
  const float* W2  = (const float*)d_in[5];
  const float* b2  = (const float*)d_in[6];
  const float* Wr  = (const float*)d_in[7];
  const float* br  = (const float*)d_in[8];

  const int N = in_sizes[0] / 128;
  const int E = in_sizes[2] / 2;

  bf16_t* Abuf = (bf16_t*)d_out;                      // [0, N*128) bf16
  bf16_t* Pbuf = (bf16_t*)d_out + (size_t)N * 128;    // [N*128, N*256) bf16

  const int nodeBlocks = (N + 63) / 64;
  const int edgeBlocks = (E + 255) / 256;
  const int nTiles     = (N + 255) / 256;
  const int NSB        = (N + 255) >> NSB_SHIFT;      // superbuckets (256 nodes)
  const int paBlocks   = (E + PA_TILE - 1) / PA_TILE;

  bf16_t* maxbf = (bf16_t*)d_ws;                      // N*256 B

  // new-path ws: maxbf + pairsBuf + srow + startB/endB + superCursor
  const size_t pairsBytes = (size_t)NSB * SBCAP * 8;
  const size_t srowBytes  = (size_t)NSB * SBCAP * 4;
  const size_t needNew = (size_t)N * 256 + pairsBytes + srowBytes +
                         (size_t)N * 8 + (size_t)NSB * 64 + 1024;

  if (ws_size >= needNew && NSB <= 256) {
    // ---------------- LDS-bucketed path ----------------
    long long* pairsBuf    = (long long*)((char*)d_ws + (size_t)N * 256);
    int*       srowN       = (int*)((char*)pairsBuf + pairsBytes);
    int*       startB      = (int*)((char*)srowN + srowBytes);
    int*       endB        = startB + N;
    int*       superCursor = endB + N;

    hipMemsetAsync(superCursor, 0, (size_t)NSB * 64, stream);
    fusedA_kernel<<<nodeBlocks + paBlocks, 256, 0, stream>>>(
        x, pos, eix, W1, b1, pairsBuf, superCursor, Abuf, Pbuf, N, E, nodeBlocks);
    passb_kernel<<<NSB, 256, 0, stream>>>(pairsBuf, superCursor, srowN,
                                          startB, endB, N);
    pernode_kernel<<<2048, 256, 0, stream>>>(Abuf, Pbuf, W2, b2, startB, endB,
                                             srowN, maxbf, N);
  } else {
    // ---------------- fallback: r7 hist+scan+scatter ----------------
    int* srow  = (int*)((char*)d_ws + (size_t)N * 256);
    int* dpad  = srow + E;
    int* start = dpad + (size_t)N * DPAD;
    int* tsum  = start + N + 1;
    int* texcl = tsum + 256;

    hipMemsetAsync(dpad, 0, (size_t)N * DPAD * 4, stream);
    fused_hist_kernel<<<nodeBlocks + edgeBlocks, 256, 0, stream>>>(
        x, pos, eix, W1, b1, dpad, Abuf, Pbuf, N, E, nodeBlocks);
    tilesum_kernel<<<nTiles, 256, 0, stream>>>(dpad, tsum, N);
    tscan_kernel<<<1, 256, 0, stream>>>(tsum, texcl, &start[N], nTiles);
    scanout_kernel<<<nTiles, 256, 0, stream>>>(dpad, texcl, start, N);
    scatter_kernel<<<edgeBlocks, 256, 0, stream>>>(eix, dpad, srow, E);
    pernode_kernel<<<2048, 256, 0, stream>>>(Abuf, Pbuf, W2, b2, start, start + 1,
                                             srow, maxbf, N);
  }

  final_gemm_kernel<<<nodeBlocks, 256, 0, stream>>>(x, Wr, br, maxbf,
                                                    (float*)d_out, N);
}